// Round 1
// baseline (172.053 us; speedup 1.0000x reference)
//
#include <hip/hip_runtime.h>

// MLPScorer: out[b,t,s] = sum_d v[d] * tanh( (h_t Wq^T + bq)[b,t,d] + (h_s Wc^T)[b,s,d] )
// B=4, T=S=D=512, all f32.
//
// Identity used: tanh(x) = 1 - 2/(1 + e^{2x}), with e^{2x} = exp2(c*x), c = 2*log2(e).
// Both GEMM outputs are pre-scaled by c so the scorer inner loop is:
//   m = a' + u'; r = rcp(1 + exp2(m)); acc += v[d]*r;  out = sumv - 2*acc.

#define B_ 4
#define T_ 512
#define S_ 512
#define D_ 512

static constexpr float C2LOG2E = 2.8853900817779268f; // 2*log2(e)

// ---------------------------------------------------------------------------
// GEMM: Out[r][e] = scale * ( dot(X[r][:], W[e][:]) + bias[e] ), K = D_ = 512
// X: [rows=2048][512] (k-contiguous), W: [512][512] (k-contiguous, i.e. x@W^T)
// 64x64 tile, 256 threads, 4x4 micro-tile, K-chunk 32.
// ---------------------------------------------------------------------------
__global__ __launch_bounds__(256) void gemm_nt_scaled(
    const float* __restrict__ X, const float* __restrict__ W,
    const float* __restrict__ bias, float* __restrict__ Out, float scale)
{
    __shared__ float Xs[32][64];   // [k][row]
    __shared__ float Ws[32][64];   // [k][col]
    const int tid = threadIdx.x;
    const int tx  = tid & 15;      // 0..15 -> col group
    const int ty  = tid >> 4;      // 0..15 -> row group
    const int r0  = blockIdx.x * 64;
    const int e0  = blockIdx.y * 64;
    const int li  = tid >> 3;          // 0..31 (staging row)
    const int lk  = (tid & 7) << 2;    // 0,4,...,28 (staging k, float4)

    float acc[4][4] = {{0.f,0.f,0.f,0.f},{0.f,0.f,0.f,0.f},
                       {0.f,0.f,0.f,0.f},{0.f,0.f,0.f,0.f}};

    for (int k0 = 0; k0 < D_; k0 += 32) {
        const float4 x0 = *(const float4*)(X + (size_t)(r0 + li)      * D_ + k0 + lk);
        const float4 x1 = *(const float4*)(X + (size_t)(r0 + li + 32) * D_ + k0 + lk);
        const float4 w0 = *(const float4*)(W + (size_t)(e0 + li)      * D_ + k0 + lk);
        const float4 w1 = *(const float4*)(W + (size_t)(e0 + li + 32) * D_ + k0 + lk);
        __syncthreads();   // protect previous chunk's LDS reads
        Xs[lk+0][li] = x0.x; Xs[lk+1][li] = x0.y; Xs[lk+2][li] = x0.z; Xs[lk+3][li] = x0.w;
        Xs[lk+0][li+32] = x1.x; Xs[lk+1][li+32] = x1.y; Xs[lk+2][li+32] = x1.z; Xs[lk+3][li+32] = x1.w;
        Ws[lk+0][li] = w0.x; Ws[lk+1][li] = w0.y; Ws[lk+2][li] = w0.z; Ws[lk+3][li] = w0.w;
        Ws[lk+0][li+32] = w1.x; Ws[lk+1][li+32] = w1.y; Ws[lk+2][li+32] = w1.z; Ws[lk+3][li+32] = w1.w;
        __syncthreads();
#pragma unroll
        for (int k = 0; k < 32; ++k) {
            const float4 a  = *(const float4*)&Xs[k][ty << 2];
            const float4 bb = *(const float4*)&Ws[k][tx << 2];
            acc[0][0] = fmaf(a.x, bb.x, acc[0][0]);
            acc[0][1] = fmaf(a.x, bb.y, acc[0][1]);
            acc[0][2] = fmaf(a.x, bb.z, acc[0][2]);
            acc[0][3] = fmaf(a.x, bb.w, acc[0][3]);
            acc[1][0] = fmaf(a.y, bb.x, acc[1][0]);
            acc[1][1] = fmaf(a.y, bb.y, acc[1][1]);
            acc[1][2] = fmaf(a.y, bb.z, acc[1][2]);
            acc[1][3] = fmaf(a.y, bb.w, acc[1][3]);
            acc[2][0] = fmaf(a.z, bb.x, acc[2][0]);
            acc[2][1] = fmaf(a.z, bb.y, acc[2][1]);
            acc[2][2] = fmaf(a.z, bb.z, acc[2][2]);
            acc[2][3] = fmaf(a.z, bb.w, acc[2][3]);
            acc[3][0] = fmaf(a.w, bb.x, acc[3][0]);
            acc[3][1] = fmaf(a.w, bb.y, acc[3][1]);
            acc[3][2] = fmaf(a.w, bb.z, acc[3][2]);
            acc[3][3] = fmaf(a.w, bb.w, acc[3][3]);
        }
    }

    float4 bv = make_float4(0.f, 0.f, 0.f, 0.f);
    if (bias) bv = *(const float4*)(bias + e0 + (tx << 2));
#pragma unroll
    for (int i = 0; i < 4; ++i) {
        float4 o;
        o.x = scale * (acc[i][0] + bv.x);
        o.y = scale * (acc[i][1] + bv.y);
        o.z = scale * (acc[i][2] + bv.z);
        o.w = scale * (acc[i][3] + bv.w);
        *(float4*)(Out + (size_t)(r0 + (ty << 2) + i) * D_ + e0 + (tx << 2)) = o;
    }
}

// ---------------------------------------------------------------------------
// Scorer: out[b,t,s] = sumv - 2 * sum_d v[d] * rcp(1 + exp2(A'[b,t,d] + U'[b,s,d]))
// Per block: one (b, 32t x 32s) tile. 256 threads, 2x2 micro-tile, d-chunk 32.
// ---------------------------------------------------------------------------
__global__ __launch_bounds__(256) void score_kernel(
    const float* __restrict__ A, const float* __restrict__ U,
    const float* __restrict__ v, float* __restrict__ out)
{
    __shared__ float As[32][32];  // [d][t]
    __shared__ float Us[32][32];  // [d][s]
    __shared__ float sred[8];
    const int tid = threadIdx.x;
    const int tx  = tid & 15;
    const int ty  = tid >> 4;
    const int b   = blockIdx.z;
    const int t0  = blockIdx.x * 32;
    const int s0  = blockIdx.y * 32;

    // sumv = sum_d v[d], once per block (wave shuffle reduce)
    float p = v[tid] + v[tid + 256];
#pragma unroll
    for (int off = 32; off > 0; off >>= 1) p += __shfl_down(p, off);
    if ((tid & 63) == 0) sred[tid >> 6] = p;

    const int li = tid >> 3;          // 0..31
    const int lk = (tid & 7) << 2;    // 0,4,...,28
    const float* Ab = A + (size_t)(b * T_ + t0) * D_;
    const float* Ub = U + (size_t)(b * S_ + s0) * D_;

    float acc00 = 0.f, acc01 = 0.f, acc10 = 0.f, acc11 = 0.f;

    for (int d0 = 0; d0 < D_; d0 += 32) {
        const float4 av = *(const float4*)(Ab + (size_t)li * D_ + d0 + lk);
        const float4 uv = *(const float4*)(Ub + (size_t)li * D_ + d0 + lk);
        __syncthreads();   // protect previous chunk's LDS reads (also orders sred)
        As[lk+0][li] = av.x; As[lk+1][li] = av.y; As[lk+2][li] = av.z; As[lk+3][li] = av.w;
        Us[lk+0][li] = uv.x; Us[lk+1][li] = uv.y; Us[lk+2][li] = uv.z; Us[lk+3][li] = uv.w;
        __syncthreads();
#pragma unroll
        for (int d = 0; d < 32; ++d) {
            const float2 a2 = *(const float2*)&As[d][ty << 1];
            const float2 u2 = *(const float2*)&Us[d][tx << 1];
            const float vd = v[d0 + d];   // wave-uniform -> scalar load path
            float m, e, r;
            m = a2.x + u2.x; e = __builtin_amdgcn_exp2f(m);
            r = __builtin_amdgcn_rcpf(e + 1.0f); acc00 = fmaf(vd, r, acc00);
            m = a2.x + u2.y; e = __builtin_amdgcn_exp2f(m);
            r = __builtin_amdgcn_rcpf(e + 1.0f); acc01 = fmaf(vd, r, acc01);
            m = a2.y + u2.x; e = __builtin_amdgcn_exp2f(m);
            r = __builtin_amdgcn_rcpf(e + 1.0f); acc10 = fmaf(vd, r, acc10);
            m = a2.y + u2.y; e = __builtin_amdgcn_exp2f(m);
            r = __builtin_amdgcn_rcpf(e + 1.0f); acc11 = fmaf(vd, r, acc11);
        }
    }

    const float sumv = sred[0] + sred[1] + sred[2] + sred[3];
    const int t = t0 + (ty << 1);
    const int s = s0 + (tx << 1);
    float2 o0, o1;
    o0.x = sumv - 2.0f * acc00;
    o0.y = sumv - 2.0f * acc01;
    o1.x = sumv - 2.0f * acc10;
    o1.y = sumv - 2.0f * acc11;
    *(float2*)(out + (size_t)(b * T_ + t)     * S_ + s) = o0;
    *(float2*)(out + (size_t)(b * T_ + t + 1) * S_ + s) = o1;
}

extern "C" void kernel_launch(void* const* d_in, const int* in_sizes, int n_in,
                              void* d_out, int out_size, void* d_ws, size_t ws_size,
                              hipStream_t stream) {
    const float* h_t = (const float*)d_in[0];  // [4,512,512]
    const float* h_s = (const float*)d_in[1];  // [4,512,512]
    const float* Wq  = (const float*)d_in[2];  // [512,512]
    const float* bq  = (const float*)d_in[3];  // [512]
    const float* Wc  = (const float*)d_in[4];  // [512,512]
    const float* v   = (const float*)d_in[5];  // [512]
    float* out = (float*)d_out;                // [4,512,512]

    float* Aq = (float*)d_ws;                  // c*(h_t Wq^T + bq): 2048*512 f32 = 4 MB
    float* Uc = Aq + (size_t)B_ * T_ * D_;     // c*(h_s Wc^T):      4 MB

    // rows = B*T = B*S = 2048 -> grid (2048/64, 512/64)
    gemm_nt_scaled<<<dim3(32, 8, 1), 256, 0, stream>>>(h_t, Wq, bq,      Aq, C2LOG2E);
    gemm_nt_scaled<<<dim3(32, 8, 1), 256, 0, stream>>>(h_s, Wc, nullptr, Uc, C2LOG2E);
    // scorer: grid (T/32, S/32, B)
    score_kernel<<<dim3(16, 16, 4), 256, 0, stream>>>(Aq, Uc, v, out);
}

// Round 2
// 99.513 us; speedup vs baseline: 1.7289x; 1.7289x over previous
//
#include <hip/hip_runtime.h>

// MLPScorer: out[b,t,s] = sum_d v[d] * tanh( (h_t Wq^T + bq)[b,t,d] + (h_s Wc^T)[b,s,d] )
// B=4, T=S=D=512, all f32.
//
// tanh(x) = 1 - 2/(1 + e^{2x}) and e^{2(a+u)} = e^{2a} * e^{2u}  (separable!).
// GEMM epilogue writes Ea = exp2(c*a), Eu = exp2(c*u), c = 2*log2(e).
// Scorer per element: q = fma(ea,eu,1); r = rcp(q); acc = fma(v_d, r, acc);
//   out = sumv - 2*acc.   -> 2 full-rate VALU + 1 trans op per element.

#define B_ 4
#define T_ 512
#define S_ 512
#define D_ 512

static constexpr float C2LOG2E = 2.8853900817779268f; // 2*log2(e)

// ---------------------------------------------------------------------------
// Fused dual GEMM + exp2 epilogue. job(blockIdx.z)==0: Ea = exp2(c*(h_t Wq^T + bq))
//                                  job==1:            Eu = exp2(c*(h_s Wc^T))
// 64x64 tile, 256 threads, 4x4 micro-tile, K-chunk 32. LDS stride 68 floats:
// 16B-aligned b128 reads, staging writes <=4-way, reads conflict-free.
// ---------------------------------------------------------------------------
__global__ __launch_bounds__(256) void gemm_exp_kernel(
    const float* __restrict__ Ht, const float* __restrict__ Hs,
    const float* __restrict__ Wq, const float* __restrict__ bq,
    const float* __restrict__ Wc,
    float* __restrict__ Ea, float* __restrict__ Eu)
{
    __shared__ float Xs[32][68];   // [k][row]
    __shared__ float Ws[32][68];   // [k][col]
    const int job = blockIdx.z;
    const float* __restrict__ X    = job ? Hs : Ht;
    const float* __restrict__ W    = job ? Wc : Wq;
    const float* __restrict__ bias = job ? nullptr : bq;
    float* __restrict__ Out        = job ? Eu : Ea;

    const int tid = threadIdx.x;
    const int tx  = tid & 15;      // col group (4 cols)
    const int ty  = tid >> 4;      // row group (4 rows)
    const int r0  = blockIdx.x * 64;
    const int e0  = blockIdx.y * 64;
    const int li  = tid >> 3;          // 0..31 staging row
    const int lk  = (tid & 7) << 2;    // 0,4,...,28 staging k

    float acc[4][4] = {{0.f,0.f,0.f,0.f},{0.f,0.f,0.f,0.f},
                       {0.f,0.f,0.f,0.f},{0.f,0.f,0.f,0.f}};

    for (int k0 = 0; k0 < D_; k0 += 32) {
        const float4 x0 = *(const float4*)(X + (size_t)(r0 + li)      * D_ + k0 + lk);
        const float4 x1 = *(const float4*)(X + (size_t)(r0 + li + 32) * D_ + k0 + lk);
        const float4 w0 = *(const float4*)(W + (size_t)(e0 + li)      * D_ + k0 + lk);
        const float4 w1 = *(const float4*)(W + (size_t)(e0 + li + 32) * D_ + k0 + lk);
        __syncthreads();   // protect previous chunk's LDS reads
        Xs[lk+0][li] = x0.x; Xs[lk+1][li] = x0.y; Xs[lk+2][li] = x0.z; Xs[lk+3][li] = x0.w;
        Xs[lk+0][li+32] = x1.x; Xs[lk+1][li+32] = x1.y; Xs[lk+2][li+32] = x1.z; Xs[lk+3][li+32] = x1.w;
        Ws[lk+0][li] = w0.x; Ws[lk+1][li] = w0.y; Ws[lk+2][li] = w0.z; Ws[lk+3][li] = w0.w;
        Ws[lk+0][li+32] = w1.x; Ws[lk+1][li+32] = w1.y; Ws[lk+2][li+32] = w1.z; Ws[lk+3][li+32] = w1.w;
        __syncthreads();
#pragma unroll
        for (int k = 0; k < 32; ++k) {
            const float4 a  = *(const float4*)&Xs[k][ty << 2];
            const float4 bb = *(const float4*)&Ws[k][tx << 2];
            acc[0][0] = fmaf(a.x, bb.x, acc[0][0]);
            acc[0][1] = fmaf(a.x, bb.y, acc[0][1]);
            acc[0][2] = fmaf(a.x, bb.z, acc[0][2]);
            acc[0][3] = fmaf(a.x, bb.w, acc[0][3]);
            acc[1][0] = fmaf(a.y, bb.x, acc[1][0]);
            acc[1][1] = fmaf(a.y, bb.y, acc[1][1]);
            acc[1][2] = fmaf(a.y, bb.z, acc[1][2]);
            acc[1][3] = fmaf(a.y, bb.w, acc[1][3]);
            acc[2][0] = fmaf(a.z, bb.x, acc[2][0]);
            acc[2][1] = fmaf(a.z, bb.y, acc[2][1]);
            acc[2][2] = fmaf(a.z, bb.z, acc[2][2]);
            acc[2][3] = fmaf(a.z, bb.w, acc[2][3]);
            acc[3][0] = fmaf(a.w, bb.x, acc[3][0]);
            acc[3][1] = fmaf(a.w, bb.y, acc[3][1]);
            acc[3][2] = fmaf(a.w, bb.z, acc[3][2]);
            acc[3][3] = fmaf(a.w, bb.w, acc[3][3]);
        }
    }

    float4 bv = make_float4(0.f, 0.f, 0.f, 0.f);
    if (bias) bv = *(const float4*)(bias + e0 + (tx << 2));
#pragma unroll
    for (int i = 0; i < 4; ++i) {
        float4 o;
        o.x = __builtin_amdgcn_exp2f(C2LOG2E * (acc[i][0] + bv.x));
        o.y = __builtin_amdgcn_exp2f(C2LOG2E * (acc[i][1] + bv.y));
        o.z = __builtin_amdgcn_exp2f(C2LOG2E * (acc[i][2] + bv.z));
        o.w = __builtin_amdgcn_exp2f(C2LOG2E * (acc[i][3] + bv.w));
        *(float4*)(Out + (size_t)(r0 + (ty << 2) + i) * D_ + e0 + (tx << 2)) = o;
    }
}

// ---------------------------------------------------------------------------
// Scorer: out[b,t,s] = sumv - 2 * sum_d v[d] * rcp(1 + Ea[b,t,d]*Eu[b,s,d])
// One (b, 32t x 32s) tile per block. 256 threads, 2x2 micro-tile, d-chunk 32.
// LDS [d][row] with stride 34: 8B-aligned b64 reads (conflict-free),
// staging writes 2-way only (free per m136).
// ---------------------------------------------------------------------------
__global__ __launch_bounds__(256) void score_kernel(
    const float* __restrict__ Ea, const float* __restrict__ Eu,
    const float* __restrict__ v, float* __restrict__ out)
{
    __shared__ float As[32][34];  // [d][t]
    __shared__ float Us[32][34];  // [d][s]
    __shared__ float sred[4];
    const int tid = threadIdx.x;
    const int tx  = tid & 15;
    const int ty  = tid >> 4;
    const int b   = blockIdx.z;
    const int t0  = blockIdx.x * 32;
    const int s0  = blockIdx.y * 32;

    // sumv once per block (wave shuffle reduce)
    float p = v[tid] + v[tid + 256];
#pragma unroll
    for (int off = 32; off > 0; off >>= 1) p += __shfl_down(p, off);
    if ((tid & 63) == 0) sred[tid >> 6] = p;

    const int li = tid >> 3;          // 0..31
    const int lk = (tid & 7) << 2;    // 0,4,...,28
    const float* Ab = Ea + (size_t)(b * T_ + t0) * D_;
    const float* Ub = Eu + (size_t)(b * S_ + s0) * D_;

    float acc00 = 0.f, acc01 = 0.f, acc10 = 0.f, acc11 = 0.f;

    for (int d0 = 0; d0 < D_; d0 += 32) {
        const float4 av = *(const float4*)(Ab + (size_t)li * D_ + d0 + lk);
        const float4 uv = *(const float4*)(Ub + (size_t)li * D_ + d0 + lk);
        __syncthreads();   // protect previous chunk's LDS reads (also orders sred)
        As[lk+0][li] = av.x; As[lk+1][li] = av.y; As[lk+2][li] = av.z; As[lk+3][li] = av.w;
        Us[lk+0][li] = uv.x; Us[lk+1][li] = uv.y; Us[lk+2][li] = uv.z; Us[lk+3][li] = uv.w;
        __syncthreads();
#pragma unroll
        for (int d = 0; d < 32; ++d) {
            const float2 a2 = *(const float2*)&As[d][ty << 1];
            const float2 u2 = *(const float2*)&Us[d][tx << 1];
            const float vd = v[d0 + d];   // wave-uniform -> scalar path
            float q, r;
            q = fmaf(a2.x, u2.x, 1.0f); r = __builtin_amdgcn_rcpf(q); acc00 = fmaf(vd, r, acc00);
            q = fmaf(a2.x, u2.y, 1.0f); r = __builtin_amdgcn_rcpf(q); acc01 = fmaf(vd, r, acc01);
            q = fmaf(a2.y, u2.x, 1.0f); r = __builtin_amdgcn_rcpf(q); acc10 = fmaf(vd, r, acc10);
            q = fmaf(a2.y, u2.y, 1.0f); r = __builtin_amdgcn_rcpf(q); acc11 = fmaf(vd, r, acc11);
        }
    }

    const float sumv = sred[0] + sred[1] + sred[2] + sred[3];
    const int t = t0 + (ty << 1);
    const int s = s0 + (tx << 1);
    float2 o0, o1;
    o0.x = sumv - 2.0f * acc00;
    o0.y = sumv - 2.0f * acc01;
    o1.x = sumv - 2.0f * acc10;
    o1.y = sumv - 2.0f * acc11;
    *(float2*)(out + (size_t)(b * T_ + t)     * S_ + s) = o0;
    *(float2*)(out + (size_t)(b * T_ + t + 1) * S_ + s) = o1;
}

extern "C" void kernel_launch(void* const* d_in, const int* in_sizes, int n_in,
                              void* d_out, int out_size, void* d_ws, size_t ws_size,
                              hipStream_t stream) {
    const float* h_t = (const float*)d_in[0];  // [4,512,512]
    const float* h_s = (const float*)d_in[1];  // [4,512,512]
    const float* Wq  = (const float*)d_in[2];  // [512,512]
    const float* bq  = (const float*)d_in[3];  // [512]
    const float* Wc  = (const float*)d_in[4];  // [512,512]
    const float* v   = (const float*)d_in[5];  // [512]
    float* out = (float*)d_out;                // [4,512,512]

    float* Ea = (float*)d_ws;                  // exp2(c*(h_t Wq^T + bq)): 4 MB
    float* Eu = Ea + (size_t)B_ * T_ * D_;     // exp2(c*(h_s Wc^T)):      4 MB

    // rows = 2048 per job -> grid (2048/64, 512/64, 2 jobs)
    gemm_exp_kernel<<<dim3(32, 8, 2), 256, 0, stream>>>(h_t, h_s, Wq, bq, Wc, Ea, Eu);
    // scorer: grid (T/32, S/32, B)
    score_kernel<<<dim3(16, 16, 4), 256, 0, stream>>>(Ea, Eu, v, out);
}

// Round 3
// 97.281 us; speedup vs baseline: 1.7686x; 1.0229x over previous
//
#include <hip/hip_runtime.h>

// MLPScorer: out[b,t,s] = sum_d v[d] * tanh( (h_t Wq^T + bq)[b,t,d] + (h_s Wc^T)[b,s,d] )
// B=4, T=S=D=512, all f32.
//
// tanh(x) = 1 - 2/(1+e^{2x});  e^{2(a+u)} = ea*eu (separable; precomputed in GEMM
// epilogue as exp2(c*...), c = 2*log2(e)).
// Scorer groups 4 consecutive d per output:
//   F_i = fma(ea_i, eu_i, 1);  sum_i v_i/F_i = num/den with
//   num = (v0*F1+v1*F0)*F2*F3 + (v2*F3+v3*F2)*F0*F1, den = F0*F1*F2*F3
// -> 14 VALU + 1 rcp per 4 elements. out = sumv - 2*acc.

#define B_ 4
#define T_ 512
#define S_ 512
#define D_ 512

static constexpr float C2LOG2E = 2.8853900817779268f; // 2*log2(e)

// ---------------------------------------------------------------------------
// Dual GEMM + exp2 epilogue, both jobs are Out = X * W^T (K = 512):
//  job0: X=h_t [2048][512], W=Wq [512][512], Out=Ea  [2048][512], bias=bq (per col)
//  job1: X=Wc  [512][512],  W=h_s [2048][512], Out=EuT [512][2048], no bias
// 64x64 tile, 256 threads, 4x4 micro-tile, K-chunk 32, padded LDS.
// ---------------------------------------------------------------------------
__global__ __launch_bounds__(256) void gemm_exp_kernel(
    const float* __restrict__ Ht, const float* __restrict__ Hs,
    const float* __restrict__ Wq, const float* __restrict__ bq,
    const float* __restrict__ Wc,
    float* __restrict__ Ea, float* __restrict__ EuT)
{
    __shared__ float Xs[32][68];   // [k][row]
    __shared__ float Ws[32][68];   // [k][col]
    const int job = blockIdx.z;
    const float* __restrict__ X = job ? Wc : Ht;
    const float* __restrict__ W = job ? Hs : Wq;
    float* __restrict__ Out     = job ? EuT : Ea;
    const int ldOut             = job ? 2048 : 512;
    const int r0 = (job ? blockIdx.y : blockIdx.x) * 64;   // X-row block
    const int e0 = (job ? blockIdx.x : blockIdx.y) * 64;   // W-row (out col) block

    const int tid = threadIdx.x;
    const int tx  = tid & 15;      // col group (4 cols)
    const int ty  = tid >> 4;      // row group (4 rows)
    const int li  = tid >> 3;          // 0..31 staging row
    const int lk  = (tid & 7) << 2;    // 0,4,...,28 staging k

    float acc[4][4] = {{0.f,0.f,0.f,0.f},{0.f,0.f,0.f,0.f},
                       {0.f,0.f,0.f,0.f},{0.f,0.f,0.f,0.f}};

    for (int k0 = 0; k0 < D_; k0 += 32) {
        const float4 x0 = *(const float4*)(X + (size_t)(r0 + li)      * D_ + k0 + lk);
        const float4 x1 = *(const float4*)(X + (size_t)(r0 + li + 32) * D_ + k0 + lk);
        const float4 w0 = *(const float4*)(W + (size_t)(e0 + li)      * D_ + k0 + lk);
        const float4 w1 = *(const float4*)(W + (size_t)(e0 + li + 32) * D_ + k0 + lk);
        __syncthreads();   // protect previous chunk's LDS reads
        Xs[lk+0][li] = x0.x; Xs[lk+1][li] = x0.y; Xs[lk+2][li] = x0.z; Xs[lk+3][li] = x0.w;
        Xs[lk+0][li+32] = x1.x; Xs[lk+1][li+32] = x1.y; Xs[lk+2][li+32] = x1.z; Xs[lk+3][li+32] = x1.w;
        Ws[lk+0][li] = w0.x; Ws[lk+1][li] = w0.y; Ws[lk+2][li] = w0.z; Ws[lk+3][li] = w0.w;
        Ws[lk+0][li+32] = w1.x; Ws[lk+1][li+32] = w1.y; Ws[lk+2][li+32] = w1.z; Ws[lk+3][li+32] = w1.w;
        __syncthreads();
#pragma unroll
        for (int k = 0; k < 32; ++k) {
            const float4 a  = *(const float4*)&Xs[k][ty << 2];
            const float4 bb = *(const float4*)&Ws[k][tx << 2];
            acc[0][0] = fmaf(a.x, bb.x, acc[0][0]);
            acc[0][1] = fmaf(a.x, bb.y, acc[0][1]);
            acc[0][2] = fmaf(a.x, bb.z, acc[0][2]);
            acc[0][3] = fmaf(a.x, bb.w, acc[0][3]);
            acc[1][0] = fmaf(a.y, bb.x, acc[1][0]);
            acc[1][1] = fmaf(a.y, bb.y, acc[1][1]);
            acc[1][2] = fmaf(a.y, bb.z, acc[1][2]);
            acc[1][3] = fmaf(a.y, bb.w, acc[1][3]);
            acc[2][0] = fmaf(a.z, bb.x, acc[2][0]);
            acc[2][1] = fmaf(a.z, bb.y, acc[2][1]);
            acc[2][2] = fmaf(a.z, bb.z, acc[2][2]);
            acc[2][3] = fmaf(a.z, bb.w, acc[2][3]);
            acc[3][0] = fmaf(a.w, bb.x, acc[3][0]);
            acc[3][1] = fmaf(a.w, bb.y, acc[3][1]);
            acc[3][2] = fmaf(a.w, bb.z, acc[3][2]);
            acc[3][3] = fmaf(a.w, bb.w, acc[3][3]);
        }
    }

    float4 bv = make_float4(0.f, 0.f, 0.f, 0.f);
    if (!job) bv = *(const float4*)(bq + e0 + (tx << 2));
#pragma unroll
    for (int i = 0; i < 4; ++i) {
        float4 o;
        o.x = __builtin_amdgcn_exp2f(C2LOG2E * (acc[i][0] + bv.x));
        o.y = __builtin_amdgcn_exp2f(C2LOG2E * (acc[i][1] + bv.y));
        o.z = __builtin_amdgcn_exp2f(C2LOG2E * (acc[i][2] + bv.z));
        o.w = __builtin_amdgcn_exp2f(C2LOG2E * (acc[i][3] + bv.w));
        *(float4*)(Out + (size_t)(r0 + (ty << 2) + i) * ldOut + e0 + (tx << 2)) = o;
    }
}

// ---------------------------------------------------------------------------
// Scorer, LDS-free. Per wave: 4 t (uniform-addr Ea/v loads) x 64 s (lane,
// coalesced EuT loads). acc_i += v4 . sigma4 via grouped rational (1 rcp / 4d).
// Block = 4 waves sharing the s-block (L1 reuse of EuT lines).
// Grid (S/64, T/16, B) = (8, 32, 4) = 1024 blocks.
// ---------------------------------------------------------------------------
__device__ __forceinline__ float grp4(float ax, float ay, float az, float aw,
                                      float u0, float u1, float u2, float u3,
                                      float4 vv, float acc)
{
    const float F0 = fmaf(ax, u0, 1.0f);
    const float F1 = fmaf(ay, u1, 1.0f);
    const float F2 = fmaf(az, u2, 1.0f);
    const float F3 = fmaf(aw, u3, 1.0f);
    const float g   = F0 * F1;
    const float h   = F2 * F3;
    const float n01 = fmaf(vv.y, F0, vv.x * F1);
    const float n23 = fmaf(vv.w, F2, vv.z * F3);
    const float num = fmaf(n23, g, n01 * h);
    const float den = g * h;
    return fmaf(num, __builtin_amdgcn_rcpf(den), acc);
}

__global__ __launch_bounds__(256) void score_kernel(
    const float* __restrict__ Ea,   // [B*T][512]
    const float* __restrict__ EuT,  // [512][B*S]
    const float* __restrict__ v, float* __restrict__ out)
{
    const int lane = threadIdx.x & 63;
    const int w    = __builtin_amdgcn_readfirstlane(threadIdx.x >> 6); // wave-uniform
    const int b    = blockIdx.z;
    const int s    = blockIdx.x * 64 + lane;
    const int t0   = blockIdx.y * 16 + w * 4;

    // sumv = sum_d v[d], butterfly reduce (all lanes end with the value)
    float p = 0.f;
#pragma unroll
    for (int k = 0; k < 8; ++k) p += v[lane + (k << 6)];
#pragma unroll
    for (int off = 32; off; off >>= 1) p += __shfl_xor(p, off);
    const float sumv = p;

    const float* __restrict__ A0 = Ea + ((size_t)(b * T_ + t0) + 0) * D_;
    const float* __restrict__ A1 = Ea + ((size_t)(b * T_ + t0) + 1) * D_;
    const float* __restrict__ A2 = Ea + ((size_t)(b * T_ + t0) + 2) * D_;
    const float* __restrict__ A3 = Ea + ((size_t)(b * T_ + t0) + 3) * D_;
    const float* __restrict__ U  = EuT + (size_t)b * S_ + s;  // row stride 2048

    float acc0 = 0.f, acc1 = 0.f, acc2 = 0.f, acc3 = 0.f;

#pragma unroll 2
    for (int d = 0; d < D_; d += 4) {
        const float u0 = U[(size_t)(d + 0) * 2048];
        const float u1 = U[(size_t)(d + 1) * 2048];
        const float u2 = U[(size_t)(d + 2) * 2048];
        const float u3 = U[(size_t)(d + 3) * 2048];
        const float4 vv = *(const float4*)(v + d);
        const float4 a0 = *(const float4*)(A0 + d);
        const float4 a1 = *(const float4*)(A1 + d);
        const float4 a2 = *(const float4*)(A2 + d);
        const float4 a3 = *(const float4*)(A3 + d);
        acc0 = grp4(a0.x, a0.y, a0.z, a0.w, u0, u1, u2, u3, vv, acc0);
        acc1 = grp4(a1.x, a1.y, a1.z, a1.w, u0, u1, u2, u3, vv, acc1);
        acc2 = grp4(a2.x, a2.y, a2.z, a2.w, u0, u1, u2, u3, vv, acc2);
        acc3 = grp4(a3.x, a3.y, a3.z, a3.w, u0, u1, u2, u3, vv, acc3);
    }

    float* __restrict__ O = out + (size_t)(b * T_ + t0) * S_ + s;
    O[0 * S_] = sumv - 2.0f * acc0;
    O[1 * S_] = sumv - 2.0f * acc1;
    O[2 * S_] = sumv - 2.0f * acc2;
    O[3 * S_] = sumv - 2.0f * acc3;
}

extern "C" void kernel_launch(void* const* d_in, const int* in_sizes, int n_in,
                              void* d_out, int out_size, void* d_ws, size_t ws_size,
                              hipStream_t stream) {
    const float* h_t = (const float*)d_in[0];  // [4,512,512]
    const float* h_s = (const float*)d_in[1];  // [4,512,512]
    const float* Wq  = (const float*)d_in[2];  // [512,512]
    const float* bq  = (const float*)d_in[3];  // [512]
    const float* Wc  = (const float*)d_in[4];  // [512,512]
    const float* v   = (const float*)d_in[5];  // [512]
    float* out = (float*)d_out;                // [4,512,512]

    float* Ea  = (float*)d_ws;                 // exp2(c*(h_t Wq^T + bq)) [2048][512]
    float* EuT = Ea + (size_t)B_ * T_ * D_;    // exp2(c*(h_s Wc^T))^T    [512][2048]

    gemm_exp_kernel<<<dim3(32, 8, 2), 256, 0, stream>>>(h_t, h_s, Wq, bq, Wc, Ea, EuT);
    score_kernel<<<dim3(8, 32, 4), 256, 0, stream>>>(Ea, EuT, v, out);
}